// Round 14
// baseline (89.662 us; speedup 1.0000x reference)
//
#include <hip/hip_runtime.h>

#define CC 128
#define HH 56
#define WW 56
#define NK2 9
#define NO 18
#define WSZ 4
#define W64 64

typedef __attribute__((ext_vector_type(8))) short short8;
typedef __attribute__((ext_vector_type(4))) float f32x4;

// ws layout:
//  wsW : ushort [9][2][4][64][8] = 73,728 B   (MFMA A-fragments)
//  xb  : ushort [4][58][58][128] = 3,444,736 B (padded channel-last bf16 x)
#define WSW_SHORTS  (9L * 2 * 4 * 64 * 8)
#define WSXB_SHORTS (4L * 58 * 58 * 128)

__device__ __forceinline__ unsigned short f2bf(float f) {
    unsigned u = __builtin_bit_cast(unsigned, f);
    u = u + 0x7fffu + ((u >> 16) & 1u);       // RNE
    return (unsigned short)(u >> 16);
}
__device__ __forceinline__ float bflo(unsigned d) {
    return __builtin_bit_cast(float, d << 16);
}
__device__ __forceinline__ float bfhi(unsigned d) {
    return __builtin_bit_cast(float, d & 0xffff0000u);
}

// ---- Kernel 0: prep (verbatim R12). blocks 0..231: x -> channel-last bf16;
//                blocks 232..375: offset_w -> MFMA A-fragments.
__global__ __launch_bounds__(256) void prep(
    const float* __restrict__ x,            // [B][C][H][W]
    const float* __restrict__ offset_w,     // [18][128][3][3]
    unsigned short* __restrict__ xb,
    unsigned short* __restrict__ wsW)
{
    const int blk = blockIdx.x;
    const int t   = threadIdx.x;
    if (blk < 232) {
        const int b  = blk / 58;
        const int hp = blk - b * 58;
        const int h  = hp - 1;
        __shared__ unsigned short s[CC][58];
        if (h >= 0 && h < HH) {
            for (int i = t; i < CC * WW; i += 256) {
                const int c = i / WW, w = i - c * WW;
                s[c][w + 1] = f2bf(x[(((long)b * CC + c) * HH + h) * WW + w]);
            }
        }
        __syncthreads();
        for (int j = t; j < 58 * CC; j += 256) {
            const int wp = j >> 7, c = j & 127;
            unsigned short v = 0;
            if (h >= 0 && h < HH && wp >= 1 && wp <= WW) v = s[c][wp];
            xb[(((long)b * 58 + hp) * 58 + wp) * CC + c] = v;
        }
    } else {
        const int e = (blk - 232) * 256 + t;
        if (e >= (int)WSW_SHORTS) return;
        const int j    = e & 7;
        const int lane = (e >> 3) & 63;
        const int kt   = (e >> 9) & 3;
        const int mt   = (e >> 11) & 1;
        const int k9   = e >> 12;
        const int o = mt * 16 + (lane & 15);
        const int c = kt * 32 + (lane >> 4) * 8 + j;
        float v = 0.f;
        if (o < NO) v = offset_w[(o * CC + c) * 9 + k9];
        wsW[e] = f2bf(v);
    }
}

// ---- Kernel A: FUSED conv(MFMA) + coef + sample, one block per (b,h) ------
// Phase 2 now reads patches from xb (bf16, pre-padded): 18 unconditional 8B
// loads/thread instead of 72 bounds-checked fp32 loads — no divergence.
__global__ __launch_bounds__(1024) void conv_sample(
    const unsigned short* __restrict__ xb,
    const unsigned short* __restrict__ wsW,
    const float* __restrict__ offset_b,
    const float* __restrict__ weight,       // [C][16]
    float* __restrict__ out)
{
    const int blk = blockIdx.x;             // b*56 + h
    const int b = blk / HH;
    const int h = blk - b * HH;
    const int t = threadIdx.x;
    const int lane = t & 63;
    const int wv = t >> 6;                  // 0..15

    __shared__ float    s_red[2][NO][W64];  // 9 KiB
    __shared__ float    s_cf[4][NK2][W64];  // 9 KiB  (4 planes: conflict-free)
    __shared__ unsigned s_id[NK2][W64];     // 2.25 KiB
    __shared__ float    s_wT[16][132];      // 8.25 KiB [j][c], 16B-aligned rows

    // stage transposed weight (covered by the phase-1 barrier)
    for (int i = t; i < 16 * CC; i += 1024) {
        const int c = i >> 4, j = i & 15;
        s_wT[j][c] = weight[c * 16 + j];
    }

    // ---------------- phase 1: MFMA offsets (R12-verified) -----------------
    const int nt  = wv & 3;
    const int mt  = (wv >> 2) & 1;
    const int kh  = wv >> 3;
    const int q   = lane >> 4;
    const int n15 = lane & 15;

    f32x4 acc = {0.f, 0.f, 0.f, 0.f};
    const int k9lo = kh ? 5 : 0;
    const int k9hi = kh ? 9 : 5;
    for (int k9 = k9lo; k9 < k9hi; ++k9) {
        const int ky = k9 / 3, kx = k9 - ky * 3;
        int col = nt * 16 + n15 + kx;
        col = col > 57 ? 57 : col;
        const unsigned short* bbase =
            xb + (((long)b * 58 + (h + ky)) * 58 + col) * CC + q * 8;
        const unsigned short* abase =
            wsW + ((long)(k9 * 2 + mt) * 4 * 64 + lane) * 8;
        #pragma unroll
        for (int kt = 0; kt < 4; ++kt) {
            short8 a  = *(const short8*)(abase + kt * 512);
            short8 bf = *(const short8*)(bbase + kt * 32);
            acc = __builtin_amdgcn_mfma_f32_16x16x32_bf16(a, bf, acc, 0, 0, 0);
        }
    }
    #pragma unroll
    for (int reg = 0; reg < 4; ++reg) {
        const int o = mt * 16 + q * 4 + reg;
        if (o < NO) s_red[kh][o][nt * 16 + n15] = acc[reg];
    }
    __syncthreads();

    // ---------------- phase 1b: coefs into LDS planes ----------------------
    if (t < NK2 * 64) {
        const int k2 = t >> 6;
        const int px = t & 63;
        const float dy = s_red[0][2 * k2][px] + s_red[1][2 * k2][px]
                       + offset_b[2 * k2];
        const float dx = s_red[0][2 * k2 + 1][px] + s_red[1][2 * k2 + 1][px]
                       + offset_b[2 * k2 + 1];
        const float yc = dy + 0.5f + (float)(k2 / 3);
        const float xc = dx + 0.5f + (float)(k2 % 3);
        const float y0 = floorf(yc), x0f = floorf(xc);
        const float fy = yc - y0, fx = xc - x0f;
        const int yi = (int)y0, xi = (int)x0f;
        float cf[4]; int id[4];
        #pragma unroll
        for (int qq = 0; qq < 4; ++qq) {
            const int oy = qq >> 1, ox = qq & 1;
            const int yy = yi + oy, xx = xi + ox;
            float c2 = (oy ? fy : 1.f - fy) * (ox ? fx : 1.f - fx);
            const bool valid = (yy >= 0) && (yy < WSZ) && (xx >= 0) && (xx < WSZ);
            cf[qq] = valid ? c2 : 0.f;
            const int yyc = yy < 0 ? 0 : (yy > 3 ? 3 : yy);
            const int xxc = xx < 0 ? 0 : (xx > 3 ? 3 : xx);
            id[qq] = yyc * 4 + xxc;
        }
        s_cf[0][k2][px] = cf[0];
        s_cf[1][k2][px] = cf[1];
        s_cf[2][k2][px] = cf[2];
        s_cf[3][k2][px] = cf[3];
        s_id[k2][px] = (unsigned)(id[0] | (id[1] << 4) | (id[2] << 8) | (id[3] << 12));
    }
    __syncthreads();

    // ---------------- phase 2: sample + patch multiply ---------------------
    if (lane < WW) {
        const int px = lane;
        const int c0 = __builtin_amdgcn_readfirstlane(wv) * 8;
        #pragma unroll
        for (int sub = 0; sub < 2; ++sub) {
            const int cb = c0 + sub * 4;
            // patches from xb: 9 unconditional 8B loads (4 bf16 channels each)
            float xv[4][9];
            #pragma unroll
            for (int ky = 0; ky < 3; ++ky) {
                #pragma unroll
                for (int kx = 0; kx < 3; ++kx) {
                    const int k = ky * 3 + kx;
                    const uint2 d = *(const uint2*)(
                        xb + (((long)b * 58 + (h + ky)) * 58 + (px + kx)) * CC + cb);
                    xv[0][k] = bflo(d.x);
                    xv[1][k] = bfhi(d.x);
                    xv[2][k] = bflo(d.y);
                    xv[3][k] = bfhi(d.y);
                }
            }
            float res[4] = {0.f, 0.f, 0.f, 0.f};
            #pragma unroll
            for (int k2 = 0; k2 < NK2; ++k2) {
                const unsigned p = s_id[k2][px];
                const float c0f = s_cf[0][k2][px];
                const float c1f = s_cf[1][k2][px];
                const float c2f = s_cf[2][k2][px];
                const float c3f = s_cf[3][k2][px];
                const float4 W0 = *(const float4*)&s_wT[p & 15][cb];
                const float4 W1 = *(const float4*)&s_wT[(p >> 4) & 15][cb];
                const float4 W2 = *(const float4*)&s_wT[(p >> 8) & 15][cb];
                const float4 W3 = *(const float4*)&s_wT[(p >> 12) & 15][cb];
                res[0] += (c0f * W0.x + c1f * W1.x + c2f * W2.x + c3f * W3.x) * xv[0][k2];
                res[1] += (c0f * W0.y + c1f * W1.y + c2f * W2.y + c3f * W3.y) * xv[1][k2];
                res[2] += (c0f * W0.z + c1f * W1.z + c2f * W2.z + c3f * W3.z) * xv[2][k2];
                res[3] += (c0f * W0.w + c1f * W1.w + c2f * W2.w + c3f * W3.w) * xv[3][k2];
            }
            #pragma unroll
            for (int u = 0; u < 4; ++u) {
                const int c = cb + u;
                out[(((long)b * CC + c) * HH + h) * WW + px] = res[u];
            }
        }
    }
}

extern "C" void kernel_launch(void* const* d_in, const int* in_sizes, int n_in,
                              void* d_out, int out_size, void* d_ws, size_t ws_size,
                              hipStream_t stream) {
    const float* x        = (const float*)d_in[0];
    const float* offset_w = (const float*)d_in[1];
    const float* offset_b = (const float*)d_in[2];
    const float* weight   = (const float*)d_in[3];
    float* out = (float*)d_out;

    char* p = (char*)d_ws;
    unsigned short* wsW = (unsigned short*)p;           p += WSW_SHORTS * 2;
    unsigned short* xb  = (unsigned short*)p;

    prep       <<<232 + 144, 256, 0, stream>>>(x, offset_w, xb, wsW);
    conv_sample<<<4 * HH, 1024, 0, stream>>>(xb, wsW, offset_b, weight, out);
}